// Round 1
// 294.627 us; speedup vs baseline: 1.1120x; 1.1120x over previous
//
#include <hip/hip_runtime.h>
#include <hip/hip_bf16.h>
#include <math.h>

#define BB 8
#define TT 2048
#define CC 1024
#define HH 64
#define NROW (BB*TT)          // 16384
#define NST (NROW*HH)         // 1048576 elements per output component
#define KK2 2048              // combined GEMM K = 2C
#define NN 384                // Bt rows (6 components)
#define GN 256                // G cols: [kr|ki|qr|qi]  (512 B rows, exact lines)
#define VTP 2080              // VT row stride in elements (4160 B, breaks 4KB aliasing)

typedef __attribute__((ext_vector_type(8))) short short8;
typedef __attribute__((ext_vector_type(4))) float f32x4;

static __device__ inline unsigned pk_bf16(float a, float b) {
    __hip_bfloat162 h = __float22bfloat162_rn(make_float2(a, b));
    unsigned u; __builtin_memcpy(&u, &h, 4); return u;
}
static __device__ inline short f2bf_s(float a) {
    __hip_bfloat16 h = __float2bfloat16(a);
    short s; __builtin_memcpy(&s, &h, 2); return s;
}
static __device__ inline short8 neg8(short8 a) {
    short8 r;
    #pragma unroll
    for (int i = 0; i < 8; ++i) r[i] = a[i] ^ (short)0x8000;
    return r;
}

// async global->LDS, 16B per lane; LDS dest is WAVE-UNIFORM base (HW adds lane*16)
static __device__ inline void async16(const void* g, void* l) {
    __builtin_amdgcn_global_load_lds(
        (const __attribute__((address_space(1))) void*)g,
        (__attribute__((address_space(3))) void*)l,
        16, 0, 0);
}

// ---------------------------------------------------------------------------
// Kernel 0: build Bt[n][k] bf16. n = 64*g + h, g in [kr,ki,qr,qi,vr,vi];
// real: [Wr;-Wi], imag: [Wi;Wr].
// ---------------------------------------------------------------------------
__global__ __launch_bounds__(256) void prep_kernel(
    const float* __restrict__ Wkr, const float* __restrict__ Wki,
    const float* __restrict__ Wqr, const float* __restrict__ Wqi,
    const float* __restrict__ Wvr, const float* __restrict__ Wvi,
    short* __restrict__ Bt)
{
    const int n = blockIdx.x;
    const int g = n >> 6, h = n & 63;
    const int p = g >> 1;
    const bool im = g & 1;
    const float* Wr = (p == 0) ? Wkr : (p == 1) ? Wqr : Wvr;
    const float* Wi = (p == 0) ? Wki : (p == 1) ? Wqi : Wvi;
    const float* W1 = im ? Wi : Wr;
    const float* W2 = im ? Wr : Wi;
    const float s2 = im ? 1.f : -1.f;

    #pragma unroll
    for (int j = 0; j < 8; ++j) {
        int k = threadIdx.x + 256 * j;
        float v = (k < CC) ? W1[k * HH + h] : s2 * W2[(k - CC) * HH + h];
        Bt[(size_t)n * KK2 + k] = f2bf_s(v);
    }
}

// ---------------------------------------------------------------------------
// Kernel 0b: convert x to bf16 once: X[row][0:1024]=xr, X[row][1024:2048]=xi.
// Pure streaming pass (192 MB), pays the fp32->bf16 cost exactly once instead
// of on every K-step of every component block.
// ---------------------------------------------------------------------------
__global__ __launch_bounds__(256) void convert_x(
    const float* __restrict__ xr, const float* __restrict__ xi,
    short* __restrict__ X)
{
    // total vec8 chunks = 16384*2048/8 = 4194304; 4096 blocks x 4 iters
    int v = blockIdx.x * 256 + threadIdx.x;
    #pragma unroll
    for (int it = 0; it < 4; ++it, v += 4096 * 256) {
        int row = v >> 8;
        int c8 = v & 255;
        const float* src = (c8 < 128) ? xr : xi;
        int col = (c8 & 127) * 8;
        const float4* p = (const float4*)&src[(size_t)row * CC + col];
        float4 a = p[0], b = p[1];
        uint4 o;
        o.x = pk_bf16(a.x, a.y);
        o.y = pk_bf16(a.z, a.w);
        o.z = pk_bf16(b.x, b.y);
        o.w = pk_bf16(b.z, b.w);
        *(uint4*)&X[(size_t)row * KK2 + c8 * 8] = o;
    }
}

// ---------------------------------------------------------------------------
// Kernel 1: bf16 MFMA GEMM, m97 structure. BM=128 BN=64 BK=64, grid (128,6).
// A and B staged with global_load_lds width=16 into LINEAR LDS; the XOR
// swizzle is applied to the GLOBAL source lane address (m173) and undone on
// the ds_read side -> conflict-free ds_read_b128.
// Epilogue identical to previous version (G tile stores / V LDS-transpose).
// ---------------------------------------------------------------------------
#define LDP 72    // epilogue G staging stride (elements)
#define STP 136   // epilogue sT row stride (elements), 16B-aligned

__global__ __launch_bounds__(256) void proj_gemm(
    const short* __restrict__ X,
    const short* __restrict__ Bt,
    short* __restrict__ G, short* __restrict__ VT)
{
    // sA [128][64] bf16 linear (16 KB) + sB [64][64] (8 KB) = 24 KB
    __shared__ __attribute__((aligned(16))) short sAB[128 * 64 + 64 * 64];
    short* sA = sAB;
    short* sB = sAB + 128 * 64;

    const int tid = threadIdx.x;
    const int mbase = blockIdx.x * 128;
    const int comp = blockIdx.y;                 // 0..5

    const int wave = tid >> 6, lane = tid & 63;
    const int wr = wave >> 1, wc = wave & 1;     // 64-row half, 32-col half
    const int quad = lane >> 4, lm = lane & 15;

    // staging lane decomposition: 8 lanes x 16B cover one 128B row
    const int lgrp = lane >> 3;                  // row within 8-row group (= row&7)
    const int lslot = lane & 7;
    const int scol = ((lslot ^ lgrp) << 4);      // swizzled byte col within row

    const char* Ag = (const char*)(X + (size_t)mbase * KK2);
    const char* Bg = (const char*)(Bt + (size_t)comp * 64 * KK2);

    f32x4 acc[4][2] = {};

    for (int ks = 0; ks < KK2 / 64; ++ks) {
        // ---- issue async stages: A-tile 16KB (4 issues/wave), B-tile 8KB (2) ----
        #pragma unroll
        for (int i = 0; i < 4; ++i) {
            int q = wave * 4 + i;                // 1KB chunk = rows q*8..q*8+7
            async16(Ag + (size_t)(q * 8 + lgrp) * (KK2 * 2) + ks * 128 + scol,
                    (char*)sA + q * 1024);
        }
        #pragma unroll
        for (int i = 0; i < 2; ++i) {
            int q = wave * 2 + i;
            async16(Bg + (size_t)(q * 8 + lgrp) * (KK2 * 2) + ks * 128 + scol,
                    (char*)sB + q * 1024);
        }
        __syncthreads();   // drains vmcnt -> tile resident

        #pragma unroll
        for (int kk = 0; kk < 2; ++kk) {
            const int cs = (kk * 32 + quad * 8) ^ ((lm & 7) << 3);  // un-swizzle
            short8 af[4], bf[2];
            #pragma unroll
            for (int mi = 0; mi < 4; ++mi)
                af[mi] = *(const short8*)&sA[(64 * wr + 16 * mi + lm) * 64 + cs];
            #pragma unroll
            for (int ni = 0; ni < 2; ++ni)
                bf[ni] = *(const short8*)&sB[(32 * wc + 16 * ni + lm) * 64 + cs];
            #pragma unroll
            for (int mi = 0; mi < 4; ++mi)
                #pragma unroll
                for (int ni = 0; ni < 2; ++ni)
                    acc[mi][ni] = __builtin_amdgcn_mfma_f32_16x16x32_bf16(
                        af[mi], bf[ni], acc[mi][ni], 0, 0, 0);
        }
        __syncthreads();   // LDS reads done before next stage overwrites
    }

    if (comp < 4) {
        // ---- stage 128x64 bf16 tile, then fully-coalesced 16B stores to G ----
        short* sG = sAB;   // [128][LDP] = 18.4 KB <= 24 KB
        #pragma unroll
        for (int mi = 0; mi < 4; ++mi)
            #pragma unroll
            for (int ni = 0; ni < 2; ++ni)
                #pragma unroll
                for (int r = 0; r < 4; ++r)
                    sG[(64*wr + 16*mi + quad*4 + r) * LDP + 32*wc + 16*ni + lm] =
                        f2bf_s(acc[mi][ni][r]);
        __syncthreads();
        #pragma unroll
        for (int j = 0; j < 4; ++j) {
            int id = tid + 256 * j;
            int row = id >> 3, c8 = id & 7;       // 8 x 16B per row
            uint4 v = *(const uint4*)&sG[row * LDP + c8 * 8];
            *(uint4*)&G[(size_t)(mbase + row) * GN + comp*64 + c8*8] = v;
        }
    } else {
        // ---- transpose 128t x 64h in LDS, coalesced 16B stores to VT ----
        short* sT = sAB;   // [64][STP] = 17.4 KB <= 24 KB
        const int vcomp = comp - 4;
        const int b = mbase >> 11;
        const int tb = mbase & 2047;
        #pragma unroll
        for (int mi = 0; mi < 4; ++mi)
            #pragma unroll
            for (int ni = 0; ni < 2; ++ni)
                #pragma unroll
                for (int r = 0; r < 4; ++r)
                    sT[(32*wc + 16*ni + lm) * STP + 64*wr + 16*mi + quad*4 + r] =
                        f2bf_s(acc[mi][ni][r]);
        __syncthreads();
        #pragma unroll
        for (int j = 0; j < 4; ++j) {
            int id = tid + 256 * j;
            int h = id >> 4, c = id & 15;         // 16 x 16B per h-row
            uint4 v = *(const uint4*)&sT[h * STP + c * 8];
            *(uint4*)&VT[(((size_t)vcomp*BB + b)*64 + h)*VTP + tb + c*8] = v;
        }
    }
}

// ---------------------------------------------------------------------------
// Kernel 2: MFMA flash attention. Wave-autonomous 16-row q-tiles; 4 waves/block
// split the k-range (kt % 4 == wave) and merge (m,l,O) via LDS at the end.
// grid = (128 q-tiles, 8 b), 256 threads, longest q-tiles first.
// ---------------------------------------------------------------------------
#define PLDS 72

__global__ __launch_bounds__(256) void attn_kernel(
    const short* __restrict__ G,
    const short* __restrict__ VT,
    float* __restrict__ out)
{
    __shared__ float comb[4][16][128];
    __shared__ float cmw[4][16], clw[4][16];

    const int tid = threadIdx.x;
    const int wave = tid >> 6, lane = tid & 63;
    const int quad = lane >> 4, lm = lane & 15;
    const int j = (int)(gridDim.x - 1) - (int)blockIdx.x;   // longest first
    const int b = blockIdx.y;
    const int qbase = j * 16;
    const int nkt = (j >> 2) + 1;    // k-tiles of 64 tokens

    const short* Qrow = G + ((size_t)(b*TT + qbase + lm)) * GN + 128;
    short8 A1[4], A2[4];
    #pragma unroll
    for (int ks = 0; ks < 4; ++ks)
        A1[ks] = *(const short8*)(Qrow + ks*32 + quad*8);
    A2[0] = A1[2]; A2[1] = A1[3];
    A2[2] = neg8(A1[0]); A2[3] = neg8(A1[1]);

    f32x4 Or[4], Oi[4];
    #pragma unroll
    for (int h = 0; h < 4; ++h)
        #pragma unroll
        for (int r = 0; r < 4; ++r) { Or[h][r] = 0.f; Oi[h][r] = 0.f; }
    float m[4], l[4];
    #pragma unroll
    for (int r = 0; r < 4; ++r) { m[r] = -INFINITY; l[r] = 0.f; }

    short* Pw = (short*)&comb[wave][0][0];
    const short* Vrb = VT + (size_t)b * 64 * VTP;
    const short* Vib = VT + ((size_t)BB + b) * 64 * VTP;

    for (int kt = wave; kt < nkt; kt += 4) {
        const int kb = kt * 64;
        const short* Kt = G + ((size_t)(b*TT + kb)) * GN;

        f32x4 mag[4];
        #pragma unroll
        for (int nt = 0; nt < 4; ++nt) {
            const short* Krow = Kt + (size_t)(nt*16 + lm) * GN;
            short8 Bf[4];
            #pragma unroll
            for (int ks = 0; ks < 4; ++ks)
                Bf[ks] = *(const short8*)(Krow + ks*32 + quad*8);
            f32x4 sr = {0.f,0.f,0.f,0.f}, si = {0.f,0.f,0.f,0.f};
            #pragma unroll
            for (int ks = 0; ks < 4; ++ks) {
                sr = __builtin_amdgcn_mfma_f32_16x16x32_bf16(A1[ks], Bf[ks], sr, 0,0,0);
                si = __builtin_amdgcn_mfma_f32_16x16x32_bf16(A2[ks], Bf[ks], si, 0,0,0);
            }
            int tok = kb + nt*16 + lm;
            #pragma unroll
            for (int r = 0; r < 4; ++r) {
                float v = sqrtf(fmaf(sr[r], sr[r], fmaf(si[r], si[r], 1e-4f))) * 0.125f;
                int qrow = qbase + quad*4 + r;
                mag[nt][r] = (tok > qrow) ? -INFINITY : v;
            }
        }

        float tm[4];
        #pragma unroll
        for (int r = 0; r < 4; ++r)
            tm[r] = fmaxf(fmaxf(mag[0][r], mag[1][r]), fmaxf(mag[2][r], mag[3][r]));
        #pragma unroll
        for (int d = 1; d < 16; d <<= 1)
            #pragma unroll
            for (int r = 0; r < 4; ++r)
                tm[r] = fmaxf(tm[r], __shfl_xor(tm[r], d, 16));

        float al[4], ps[4];
        #pragma unroll
        for (int r = 0; r < 4; ++r) {
            float mn = fmaxf(m[r], tm[r]);
            al[r] = __expf(m[r] - mn);
            m[r] = mn;
            ps[r] = 0.f;
        }
        #pragma unroll
        for (int nt = 0; nt < 4; ++nt)
            #pragma unroll
            for (int r = 0; r < 4; ++r) {
                float p = __expf(mag[nt][r] - m[r]);
                mag[nt][r] = p;
                ps[r] += p;
            }
        #pragma unroll
        for (int d = 1; d < 16; d <<= 1)
            #pragma unroll
            for (int r = 0; r < 4; ++r)
                ps[r] += __shfl_xor(ps[r], d, 16);
        #pragma unroll
        for (int r = 0; r < 4; ++r)
            l[r] = fmaf(l[r], al[r], ps[r]);

        #pragma unroll
        for (int h = 0; h < 4; ++h)
            #pragma unroll
            for (int r = 0; r < 4; ++r) { Or[h][r] *= al[r]; Oi[h][r] *= al[r]; }

        #pragma unroll
        for (int nt = 0; nt < 4; ++nt)
            #pragma unroll
            for (int r = 0; r < 4; ++r)
                Pw[(quad*4 + r) * PLDS + nt*16 + lm] = f2bf_s(mag[nt][r]);
        short8 Af0 = *(const short8*)&Pw[lm * PLDS + quad*8];
        short8 Af1 = *(const short8*)&Pw[lm * PLDS + 32 + quad*8];

        #pragma unroll
        for (int ht = 0; ht < 4; ++ht) {
            const short* vr0 = Vrb + (size_t)(ht*16 + lm) * VTP + kb + quad*8;
            const short* vi0 = Vib + (size_t)(ht*16 + lm) * VTP + kb + quad*8;
            short8 br0 = *(const short8*)(vr0);
            short8 br1 = *(const short8*)(vr0 + 32);
            short8 bi0 = *(const short8*)(vi0);
            short8 bi1 = *(const short8*)(vi0 + 32);
            Or[ht] = __builtin_amdgcn_mfma_f32_16x16x32_bf16(Af0, br0, Or[ht], 0,0,0);
            Or[ht] = __builtin_amdgcn_mfma_f32_16x16x32_bf16(Af1, br1, Or[ht], 0,0,0);
            Oi[ht] = __builtin_amdgcn_mfma_f32_16x16x32_bf16(Af0, bi0, Oi[ht], 0,0,0);
            Oi[ht] = __builtin_amdgcn_mfma_f32_16x16x32_bf16(Af1, bi1, Oi[ht], 0,0,0);
        }
    }

    __syncthreads();

    #pragma unroll
    for (int ht = 0; ht < 4; ++ht)
        #pragma unroll
        for (int r = 0; r < 4; ++r) {
            comb[wave][quad*4 + r][ht*16 + lm]      = Or[ht][r];
            comb[wave][quad*4 + r][64 + ht*16 + lm] = Oi[ht][r];
        }
    if (lm == 0) {
        #pragma unroll
        for (int r = 0; r < 4; ++r) {
            cmw[wave][quad*4 + r] = m[r];
            clw[wave][quad*4 + r] = l[r];
        }
    }
    __syncthreads();

    for (int e = tid; e < 16*128; e += 256) {
        int q = e >> 7, h = e & 127;
        float mstar = fmaxf(fmaxf(cmw[0][q], cmw[1][q]), fmaxf(cmw[2][q], cmw[3][q]));
        float osum = 0.f, lsum = 0.f;
        #pragma unroll
        for (int w = 0; w < 4; ++w) {
            float f = __expf(cmw[w][q] - mstar);
            osum = fmaf(f, comb[w][q][h], osum);
            lsum = fmaf(f, clw[w][q], lsum);
        }
        float res = osum / lsum;
        int comp = h >> 6, hh = h & 63;
        out[(size_t)comp * NST + ((size_t)(b*TT + qbase + q)) * HH + hh] = res;
    }
}

extern "C" void kernel_launch(void* const* d_in, const int* in_sizes, int n_in,
                              void* d_out, int out_size, void* d_ws, size_t ws_size,
                              hipStream_t stream)
{
    const float* xr  = (const float*)d_in[0];
    const float* xi  = (const float*)d_in[1];
    const float* Wkr = (const float*)d_in[2];
    const float* Wki = (const float*)d_in[3];
    const float* Wqr = (const float*)d_in[4];
    const float* Wqi = (const float*)d_in[5];
    const float* Wvr = (const float*)d_in[6];
    const float* Wvi = (const float*)d_in[7];

    short* Bt = (short*)d_ws;                               // 1.5 MB
    short* G  = (short*)((char*)d_ws + (2u  << 20));        // 8 MB  [16384][256]
    short* VT = (short*)((char*)d_ws + (11u << 20));        // 4.3 MB [2][8][64][VTP]
    short* X  = (short*)((char*)d_ws + (16u << 20));        // 64 MB [16384][2048] bf16
    float* out = (float*)d_out;

    prep_kernel<<<NN, 256, 0, stream>>>(Wkr, Wki, Wqr, Wqi, Wvr, Wvi, Bt);

    convert_x<<<4096, 256, 0, stream>>>(xr, xi, X);

    dim3 g1(NROW / 128, 6);
    proj_gemm<<<g1, 256, 0, stream>>>(X, Bt, G, VT);

    dim3 g3(TT / 16, BB);
    attn_kernel<<<g3, 256, 0, stream>>>(G, VT, out);
}

// Round 2
// 282.799 us; speedup vs baseline: 1.1585x; 1.0418x over previous
//
#include <hip/hip_runtime.h>
#include <hip/hip_bf16.h>
#include <math.h>

#define BB 8
#define TT 2048
#define CC 1024
#define HH 64
#define NROW (BB*TT)          // 16384
#define NST (NROW*HH)         // 1048576 elements per output component
#define KK2 2048              // combined GEMM K = 2C
#define NN 384                // Bt rows (6 components)
#define GN 256                // G cols: [kr|ki|qr|qi]  (512 B rows, exact lines)
#define VTP 2080              // VT row stride in elements (4160 B, breaks 4KB aliasing)

typedef __attribute__((ext_vector_type(8))) short short8;
typedef __attribute__((ext_vector_type(4))) float f32x4;

static __device__ inline unsigned pk_bf16(float a, float b) {
    __hip_bfloat162 h = __float22bfloat162_rn(make_float2(a, b));
    unsigned u; __builtin_memcpy(&u, &h, 4); return u;
}
static __device__ inline short f2bf_s(float a) {
    __hip_bfloat16 h = __float2bfloat16(a);
    short s; __builtin_memcpy(&s, &h, 2); return s;
}
static __device__ inline short8 neg8(short8 a) {
    short8 r;
    #pragma unroll
    for (int i = 0; i < 8; ++i) r[i] = a[i] ^ (short)0x8000;
    return r;
}

// async global->LDS, 16B per lane; LDS dest is WAVE-UNIFORM base (HW adds lane*16)
static __device__ inline void async16(const void* g, void* l) {
    __builtin_amdgcn_global_load_lds(
        (const __attribute__((address_space(1))) void*)g,
        (__attribute__((address_space(3))) void*)l,
        16, 0, 0);
}

// ---------------------------------------------------------------------------
// Kernel 0: build Bt[n][k] bf16. n = 64*g + h, g in [kr,ki,qr,qi,vr,vi];
// real: [Wr;-Wi], imag: [Wi;Wr].
// ---------------------------------------------------------------------------
__global__ __launch_bounds__(256) void prep_kernel(
    const float* __restrict__ Wkr, const float* __restrict__ Wki,
    const float* __restrict__ Wqr, const float* __restrict__ Wqi,
    const float* __restrict__ Wvr, const float* __restrict__ Wvi,
    short* __restrict__ Bt)
{
    const int n = blockIdx.x;
    const int g = n >> 6, h = n & 63;
    const int p = g >> 1;
    const bool im = g & 1;
    const float* Wr = (p == 0) ? Wkr : (p == 1) ? Wqr : Wvr;
    const float* Wi = (p == 0) ? Wki : (p == 1) ? Wqi : Wvi;
    const float* W1 = im ? Wi : Wr;
    const float* W2 = im ? Wr : Wi;
    const float s2 = im ? 1.f : -1.f;

    #pragma unroll
    for (int j = 0; j < 8; ++j) {
        int k = threadIdx.x + 256 * j;
        float v = (k < CC) ? W1[k * HH + h] : s2 * W2[(k - CC) * HH + h];
        Bt[(size_t)n * KK2 + k] = f2bf_s(v);
    }
}

// ---------------------------------------------------------------------------
// Kernel 0b: convert x to bf16 once: X[row][0:1024]=xr, X[row][1024:2048]=xi.
// ---------------------------------------------------------------------------
__global__ __launch_bounds__(256) void convert_x(
    const float* __restrict__ xr, const float* __restrict__ xi,
    short* __restrict__ X)
{
    int v = blockIdx.x * 256 + threadIdx.x;
    #pragma unroll
    for (int it = 0; it < 4; ++it, v += 4096 * 256) {
        int row = v >> 8;
        int c8 = v & 255;
        const float* src = (c8 < 128) ? xr : xi;
        int col = (c8 & 127) * 8;
        const float4* p = (const float4*)&src[(size_t)row * CC + col];
        float4 a = p[0], b = p[1];
        uint4 o;
        o.x = pk_bf16(a.x, a.y);
        o.y = pk_bf16(a.z, a.w);
        o.z = pk_bf16(b.x, b.y);
        o.w = pk_bf16(b.z, b.w);
        *(uint4*)&X[(size_t)row * KK2 + c8 * 8] = o;
    }
}

// ---------------------------------------------------------------------------
// Kernel 1: bf16 MFMA GEMM, m97 structure. BM=128 BN=64 BK=64, grid (128,6).
// global_load_lds width=16 with pre-swizzled global source (m173), un-swizzled
// on the ds_read side -> conflict-free ds_read_b128.
// ---------------------------------------------------------------------------
#define LDP 72    // epilogue G staging stride (elements)
#define STP 136   // epilogue sT row stride (elements), 16B-aligned

__global__ __launch_bounds__(256) void proj_gemm(
    const short* __restrict__ X,
    const short* __restrict__ Bt,
    short* __restrict__ G, short* __restrict__ VT)
{
    __shared__ __attribute__((aligned(16))) short sAB[128 * 64 + 64 * 64];
    short* sA = sAB;
    short* sB = sAB + 128 * 64;

    const int tid = threadIdx.x;
    const int mbase = blockIdx.x * 128;
    const int comp = blockIdx.y;                 // 0..5

    const int wave = tid >> 6, lane = tid & 63;
    const int wr = wave >> 1, wc = wave & 1;     // 64-row half, 32-col half
    const int quad = lane >> 4, lm = lane & 15;

    const int lgrp = lane >> 3;                  // row within 8-row group (= row&7)
    const int lslot = lane & 7;
    const int scol = ((lslot ^ lgrp) << 4);      // swizzled byte col within row

    const char* Ag = (const char*)(X + (size_t)mbase * KK2);
    const char* Bg = (const char*)(Bt + (size_t)comp * 64 * KK2);

    f32x4 acc[4][2] = {};

    for (int ks = 0; ks < KK2 / 64; ++ks) {
        #pragma unroll
        for (int i = 0; i < 4; ++i) {
            int q = wave * 4 + i;                // 1KB chunk = rows q*8..q*8+7
            async16(Ag + (size_t)(q * 8 + lgrp) * (KK2 * 2) + ks * 128 + scol,
                    (char*)sA + q * 1024);
        }
        #pragma unroll
        for (int i = 0; i < 2; ++i) {
            int q = wave * 2 + i;
            async16(Bg + (size_t)(q * 8 + lgrp) * (KK2 * 2) + ks * 128 + scol,
                    (char*)sB + q * 1024);
        }
        __syncthreads();   // drains vmcnt -> tile resident

        #pragma unroll
        for (int kk = 0; kk < 2; ++kk) {
            const int cs = (kk * 32 + quad * 8) ^ ((lm & 7) << 3);  // un-swizzle
            short8 af[4], bf[2];
            #pragma unroll
            for (int mi = 0; mi < 4; ++mi)
                af[mi] = *(const short8*)&sA[(64 * wr + 16 * mi + lm) * 64 + cs];
            #pragma unroll
            for (int ni = 0; ni < 2; ++ni)
                bf[ni] = *(const short8*)&sB[(32 * wc + 16 * ni + lm) * 64 + cs];
            #pragma unroll
            for (int mi = 0; mi < 4; ++mi)
                #pragma unroll
                for (int ni = 0; ni < 2; ++ni)
                    acc[mi][ni] = __builtin_amdgcn_mfma_f32_16x16x32_bf16(
                        af[mi], bf[ni], acc[mi][ni], 0, 0, 0);
        }
        __syncthreads();   // LDS reads done before next stage overwrites
    }

    if (comp < 4) {
        short* sG = sAB;   // [128][LDP]
        #pragma unroll
        for (int mi = 0; mi < 4; ++mi)
            #pragma unroll
            for (int ni = 0; ni < 2; ++ni)
                #pragma unroll
                for (int r = 0; r < 4; ++r)
                    sG[(64*wr + 16*mi + quad*4 + r) * LDP + 32*wc + 16*ni + lm] =
                        f2bf_s(acc[mi][ni][r]);
        __syncthreads();
        #pragma unroll
        for (int j = 0; j < 4; ++j) {
            int id = tid + 256 * j;
            int row = id >> 3, c8 = id & 7;       // 8 x 16B per row
            uint4 v = *(const uint4*)&sG[row * LDP + c8 * 8];
            *(uint4*)&G[(size_t)(mbase + row) * GN + comp*64 + c8*8] = v;
        }
    } else {
        short* sT = sAB;   // [64][STP]
        const int vcomp = comp - 4;
        const int b = mbase >> 11;
        const int tb = mbase & 2047;
        #pragma unroll
        for (int mi = 0; mi < 4; ++mi)
            #pragma unroll
            for (int ni = 0; ni < 2; ++ni)
                #pragma unroll
                for (int r = 0; r < 4; ++r)
                    sT[(32*wc + 16*ni + lm) * STP + 64*wr + 16*mi + quad*4 + r] =
                        f2bf_s(acc[mi][ni][r]);
        __syncthreads();
        #pragma unroll
        for (int j = 0; j < 4; ++j) {
            int id = tid + 256 * j;
            int h = id >> 4, c = id & 15;         // 16 x 16B per h-row
            uint4 v = *(const uint4*)&sT[h * STP + c * 8];
            *(uint4*)&VT[(((size_t)vcomp*BB + b)*64 + h)*VTP + tb + c*8] = v;
        }
    }
}

// ---------------------------------------------------------------------------
// Kernel 2: MFMA flash attention, log2-domain online softmax.
//  - row-sum l via ones-MFMA (replaces 16-shfl sum tree + l updates)
//  - defer-max (T13): rescale only when tile max exceeds m+8 (log2 units)
//  - raw v_sqrt_f32 / v_exp_f32 (no libm fixup sequences)
//  - s_setprio(1) around MFMA clusters (T5)
// ---------------------------------------------------------------------------
#define PLDS 72
#define SC2 0.18033688f      // 0.125 * log2(e): softmax in exp2 domain

__global__ __launch_bounds__(256) void attn_kernel(
    const short* __restrict__ G,
    const short* __restrict__ VT,
    float* __restrict__ out)
{
    __shared__ float comb[4][16][128];
    __shared__ float cmw[4][16], clw[4][16];

    const int tid = threadIdx.x;
    const int wave = tid >> 6, lane = tid & 63;
    const int quad = lane >> 4, lm = lane & 15;
    const int j = (int)(gridDim.x - 1) - (int)blockIdx.x;   // longest first
    const int b = blockIdx.y;
    const int qbase = j * 16;
    const int nkt = (j >> 2) + 1;    // k-tiles of 64 tokens

    const short* Qrow = G + ((size_t)(b*TT + qbase + lm)) * GN + 128;
    short8 A1[4], A2[4];
    #pragma unroll
    for (int ks = 0; ks < 4; ++ks)
        A1[ks] = *(const short8*)(Qrow + ks*32 + quad*8);
    A2[0] = A1[2]; A2[1] = A1[3];
    A2[2] = neg8(A1[0]); A2[3] = neg8(A1[1]);

    short8 ones;
    #pragma unroll
    for (int i = 0; i < 8; ++i) ones[i] = (short)0x3F80;   // bf16 1.0

    f32x4 Or[4], Oi[4];
    #pragma unroll
    for (int h = 0; h < 4; ++h)
        #pragma unroll
        for (int r = 0; r < 4; ++r) { Or[h][r] = 0.f; Oi[h][r] = 0.f; }
    f32x4 Ol = {0.f, 0.f, 0.f, 0.f};            // row-sums via ones-MFMA
    float m[4];
    #pragma unroll
    for (int r = 0; r < 4; ++r) m[r] = -INFINITY;

    short* Pw = (short*)&comb[wave][0][0];
    const short* Vrb = VT + (size_t)b * 64 * VTP;
    const short* Vib = VT + ((size_t)BB + b) * 64 * VTP;

    for (int kt = wave; kt < nkt; kt += 4) {
        const int kb = kt * 64;
        const short* Kt = G + ((size_t)(b*TT + kb)) * GN;

        f32x4 mag[4];
        #pragma unroll
        for (int nt = 0; nt < 4; ++nt) {
            const short* Krow = Kt + (size_t)(nt*16 + lm) * GN;
            short8 Bf[4];
            #pragma unroll
            for (int ks = 0; ks < 4; ++ks)
                Bf[ks] = *(const short8*)(Krow + ks*32 + quad*8);
            f32x4 sr = {0.f,0.f,0.f,0.f}, si = {0.f,0.f,0.f,0.f};
            __builtin_amdgcn_s_setprio(1);
            #pragma unroll
            for (int ks = 0; ks < 4; ++ks) {
                sr = __builtin_amdgcn_mfma_f32_16x16x32_bf16(A1[ks], Bf[ks], sr, 0,0,0);
                si = __builtin_amdgcn_mfma_f32_16x16x32_bf16(A2[ks], Bf[ks], si, 0,0,0);
            }
            __builtin_amdgcn_s_setprio(0);
            int tok = kb + nt*16 + lm;
            #pragma unroll
            for (int r = 0; r < 4; ++r) {
                float v = __builtin_amdgcn_sqrtf(
                              fmaf(sr[r], sr[r], fmaf(si[r], si[r], 1e-4f))) * SC2;
                int qrow = qbase + quad*4 + r;
                mag[nt][r] = (tok > qrow) ? -INFINITY : v;
            }
        }

        float tm[4];
        #pragma unroll
        for (int r = 0; r < 4; ++r)
            tm[r] = fmaxf(fmaxf(mag[0][r], mag[1][r]), fmaxf(mag[2][r], mag[3][r]));
        #pragma unroll
        for (int d = 1; d < 16; d <<= 1)
            #pragma unroll
            for (int r = 0; r < 4; ++r)
                tm[r] = fmaxf(tm[r], __shfl_xor(tm[r], d, 16));

        // defer-max: rescale only when the running max actually grows past slack
        int need = (tm[0] > m[0] + 8.f) | (tm[1] > m[1] + 8.f) |
                   (tm[2] > m[2] + 8.f) | (tm[3] > m[3] + 8.f);
        if (__any(need)) {
            float al[4];
            #pragma unroll
            for (int r = 0; r < 4; ++r) {
                float mn = fmaxf(m[r], tm[r]);
                al[r] = __builtin_amdgcn_exp2f(m[r] - mn);
                m[r] = mn;
            }
            #pragma unroll
            for (int h = 0; h < 4; ++h)
                #pragma unroll
                for (int r = 0; r < 4; ++r) { Or[h][r] *= al[r]; Oi[h][r] *= al[r]; }
            #pragma unroll
            for (int r = 0; r < 4; ++r) Ol[r] *= al[r];
        }

        #pragma unroll
        for (int nt = 0; nt < 4; ++nt)
            #pragma unroll
            for (int r = 0; r < 4; ++r) {
                float p = __builtin_amdgcn_exp2f(mag[nt][r] - m[r]);
                Pw[(quad*4 + r) * PLDS + nt*16 + lm] = f2bf_s(p);
            }
        short8 Af0 = *(const short8*)&Pw[lm * PLDS + quad*8];
        short8 Af1 = *(const short8*)&Pw[lm * PLDS + 32 + quad*8];

        __builtin_amdgcn_s_setprio(1);
        Ol = __builtin_amdgcn_mfma_f32_16x16x32_bf16(Af0, ones, Ol, 0,0,0);
        Ol = __builtin_amdgcn_mfma_f32_16x16x32_bf16(Af1, ones, Ol, 0,0,0);
        __builtin_amdgcn_s_setprio(0);

        #pragma unroll
        for (int ht = 0; ht < 4; ++ht) {
            const short* vr0 = Vrb + (size_t)(ht*16 + lm) * VTP + kb + quad*8;
            const short* vi0 = Vib + (size_t)(ht*16 + lm) * VTP + kb + quad*8;
            short8 br0 = *(const short8*)(vr0);
            short8 br1 = *(const short8*)(vr0 + 32);
            short8 bi0 = *(const short8*)(vi0);
            short8 bi1 = *(const short8*)(vi0 + 32);
            __builtin_amdgcn_s_setprio(1);
            Or[ht] = __builtin_amdgcn_mfma_f32_16x16x32_bf16(Af0, br0, Or[ht], 0,0,0);
            Or[ht] = __builtin_amdgcn_mfma_f32_16x16x32_bf16(Af1, br1, Or[ht], 0,0,0);
            Oi[ht] = __builtin_amdgcn_mfma_f32_16x16x32_bf16(Af0, bi0, Oi[ht], 0,0,0);
            Oi[ht] = __builtin_amdgcn_mfma_f32_16x16x32_bf16(Af1, bi1, Oi[ht], 0,0,0);
            __builtin_amdgcn_s_setprio(0);
        }
    }

    __syncthreads();

    #pragma unroll
    for (int ht = 0; ht < 4; ++ht)
        #pragma unroll
        for (int r = 0; r < 4; ++r) {
            comb[wave][quad*4 + r][ht*16 + lm]      = Or[ht][r];
            comb[wave][quad*4 + r][64 + ht*16 + lm] = Oi[ht][r];
        }
    if (lm == 0) {
        #pragma unroll
        for (int r = 0; r < 4; ++r) {
            cmw[wave][quad*4 + r] = m[r];
            clw[wave][quad*4 + r] = Ol[r];
        }
    }
    __syncthreads();

    for (int e = tid; e < 16*128; e += 256) {
        int q = e >> 7, h = e & 127;
        float mstar = fmaxf(fmaxf(cmw[0][q], cmw[1][q]), fmaxf(cmw[2][q], cmw[3][q]));
        float osum = 0.f, lsum = 0.f;
        #pragma unroll
        for (int w = 0; w < 4; ++w) {
            float f = __builtin_amdgcn_exp2f(cmw[w][q] - mstar);
            osum = fmaf(f, comb[w][q][h], osum);
            lsum = fmaf(f, clw[w][q], lsum);
        }
        float res = osum / lsum;
        int comp = h >> 6, hh = h & 63;
        out[(size_t)comp * NST + ((size_t)(b*TT + qbase + q)) * HH + hh] = res;
    }
}

extern "C" void kernel_launch(void* const* d_in, const int* in_sizes, int n_in,
                              void* d_out, int out_size, void* d_ws, size_t ws_size,
                              hipStream_t stream)
{
    const float* xr  = (const float*)d_in[0];
    const float* xi  = (const float*)d_in[1];
    const float* Wkr = (const float*)d_in[2];
    const float* Wki = (const float*)d_in[3];
    const float* Wqr = (const float*)d_in[4];
    const float* Wqi = (const float*)d_in[5];
    const float* Wvr = (const float*)d_in[6];
    const float* Wvi = (const float*)d_in[7];

    short* Bt = (short*)d_ws;                               // 1.5 MB
    short* G  = (short*)((char*)d_ws + (2u  << 20));        // 8 MB  [16384][256]
    short* VT = (short*)((char*)d_ws + (11u << 20));        // 4.3 MB [2][8][64][VTP]
    short* X  = (short*)((char*)d_ws + (16u << 20));        // 64 MB [16384][2048] bf16
    float* out = (float*)d_out;

    prep_kernel<<<NN, 256, 0, stream>>>(Wkr, Wki, Wqr, Wqi, Wvr, Wvi, Bt);

    convert_x<<<4096, 256, 0, stream>>>(xr, xi, X);

    dim3 g1(NROW / 128, 6);
    proj_gemm<<<g1, 256, 0, stream>>>(X, Bt, G, VT);

    dim3 g3(TT / 16, BB);
    attn_kernel<<<g3, 256, 0, stream>>>(G, VT, out);
}

// Round 3
// 259.975 us; speedup vs baseline: 1.2602x; 1.0878x over previous
//
#include <hip/hip_runtime.h>
#include <hip/hip_bf16.h>
#include <math.h>

#define BB 8
#define TT 2048
#define CC 1024
#define HH 64
#define NROW (BB*TT)          // 16384
#define NST (NROW*HH)         // 1048576 elements per output component
#define KK2 2048              // combined GEMM K = 2C
#define NN 384                // Bt rows (6 components)
#define GN 256                // G cols: [kr|ki|qr|qi]  (512 B rows, exact lines)
#define VTP 2080              // VT row stride in elements (4160 B, breaks 4KB aliasing)

typedef __attribute__((ext_vector_type(8))) short short8;
typedef __attribute__((ext_vector_type(4))) float f32x4;

static __device__ inline unsigned pk_bf16(float a, float b) {
    __hip_bfloat162 h = __float22bfloat162_rn(make_float2(a, b));
    unsigned u; __builtin_memcpy(&u, &h, 4); return u;
}
static __device__ inline short f2bf_s(float a) {
    __hip_bfloat16 h = __float2bfloat16(a);
    short s; __builtin_memcpy(&s, &h, 2); return s;
}
static __device__ inline short8 neg8(short8 a) {
    short8 r;
    #pragma unroll
    for (int i = 0; i < 8; ++i) r[i] = a[i] ^ (short)0x8000;
    return r;
}

// async global->LDS, 16B per lane; LDS dest is WAVE-UNIFORM base (HW adds lane*16)
static __device__ inline void async16(const void* g, void* l) {
    __builtin_amdgcn_global_load_lds(
        (const __attribute__((address_space(1))) void*)g,
        (__attribute__((address_space(3))) void*)l,
        16, 0, 0);
}

// ---------------------------------------------------------------------------
// Kernel 0: build Bt[n][k] bf16. n = 64*g + h, g in [kr,ki,qr,qi,vr,vi];
// real: [Wr;-Wi], imag: [Wi;Wr].
// ---------------------------------------------------------------------------
__global__ __launch_bounds__(256) void prep_kernel(
    const float* __restrict__ Wkr, const float* __restrict__ Wki,
    const float* __restrict__ Wqr, const float* __restrict__ Wqi,
    const float* __restrict__ Wvr, const float* __restrict__ Wvi,
    short* __restrict__ Bt)
{
    const int n = blockIdx.x;
    const int g = n >> 6, h = n & 63;
    const int p = g >> 1;
    const bool im = g & 1;
    const float* Wr = (p == 0) ? Wkr : (p == 1) ? Wqr : Wvr;
    const float* Wi = (p == 0) ? Wki : (p == 1) ? Wqi : Wvi;
    const float* W1 = im ? Wi : Wr;
    const float* W2 = im ? Wr : Wi;
    const float s2 = im ? 1.f : -1.f;

    #pragma unroll
    for (int j = 0; j < 8; ++j) {
        int k = threadIdx.x + 256 * j;
        float v = (k < CC) ? W1[k * HH + h] : s2 * W2[(k - CC) * HH + h];
        Bt[(size_t)n * KK2 + k] = f2bf_s(v);
    }
}

// ---------------------------------------------------------------------------
// Kernel 0b: convert x to bf16 once: X[row][0:1024]=xr, X[row][1024:2048]=xi.
// ---------------------------------------------------------------------------
__global__ __launch_bounds__(256) void convert_x(
    const float* __restrict__ xr, const float* __restrict__ xi,
    short* __restrict__ X)
{
    int v = blockIdx.x * 256 + threadIdx.x;
    #pragma unroll
    for (int it = 0; it < 4; ++it, v += 4096 * 256) {
        int row = v >> 8;
        int c8 = v & 255;
        const float* src = (c8 < 128) ? xr : xi;
        int col = (c8 & 127) * 8;
        const float4* p = (const float4*)&src[(size_t)row * CC + col];
        float4 a = p[0], b = p[1];
        uint4 o;
        o.x = pk_bf16(a.x, a.y);
        o.y = pk_bf16(a.z, a.w);
        o.z = pk_bf16(b.x, b.y);
        o.w = pk_bf16(b.z, b.w);
        *(uint4*)&X[(size_t)row * KK2 + c8 * 8] = o;
    }
}

// ---------------------------------------------------------------------------
// Kernel 1: bf16 MFMA GEMM, m97 structure. BM=128 BN=64 BK=64, grid (128,6).
// global_load_lds width=16 with pre-swizzled global source (m173), un-swizzled
// on the ds_read side -> conflict-free ds_read_b128.
// ---------------------------------------------------------------------------
#define LDP 72    // epilogue G staging stride (elements)
#define STP 136   // epilogue sT row stride (elements), 16B-aligned

__global__ __launch_bounds__(256) void proj_gemm(
    const short* __restrict__ X,
    const short* __restrict__ Bt,
    short* __restrict__ G, short* __restrict__ VT)
{
    __shared__ __attribute__((aligned(16))) short sAB[128 * 64 + 64 * 64];
    short* sA = sAB;
    short* sB = sAB + 128 * 64;

    const int tid = threadIdx.x;
    const int mbase = blockIdx.x * 128;
    const int comp = blockIdx.y;                 // 0..5

    const int wave = tid >> 6, lane = tid & 63;
    const int wr = wave >> 1, wc = wave & 1;     // 64-row half, 32-col half
    const int quad = lane >> 4, lm = lane & 15;

    const int lgrp = lane >> 3;                  // row within 8-row group (= row&7)
    const int lslot = lane & 7;
    const int scol = ((lslot ^ lgrp) << 4);      // swizzled byte col within row

    const char* Ag = (const char*)(X + (size_t)mbase * KK2);
    const char* Bg = (const char*)(Bt + (size_t)comp * 64 * KK2);

    f32x4 acc[4][2] = {};

    for (int ks = 0; ks < KK2 / 64; ++ks) {
        #pragma unroll
        for (int i = 0; i < 4; ++i) {
            int q = wave * 4 + i;                // 1KB chunk = rows q*8..q*8+7
            async16(Ag + (size_t)(q * 8 + lgrp) * (KK2 * 2) + ks * 128 + scol,
                    (char*)sA + q * 1024);
        }
        #pragma unroll
        for (int i = 0; i < 2; ++i) {
            int q = wave * 2 + i;
            async16(Bg + (size_t)(q * 8 + lgrp) * (KK2 * 2) + ks * 128 + scol,
                    (char*)sB + q * 1024);
        }
        __syncthreads();   // drains vmcnt -> tile resident

        #pragma unroll
        for (int kk = 0; kk < 2; ++kk) {
            const int cs = (kk * 32 + quad * 8) ^ ((lm & 7) << 3);  // un-swizzle
            short8 af[4], bf[2];
            #pragma unroll
            for (int mi = 0; mi < 4; ++mi)
                af[mi] = *(const short8*)&sA[(64 * wr + 16 * mi + lm) * 64 + cs];
            #pragma unroll
            for (int ni = 0; ni < 2; ++ni)
                bf[ni] = *(const short8*)&sB[(32 * wc + 16 * ni + lm) * 64 + cs];
            #pragma unroll
            for (int mi = 0; mi < 4; ++mi)
                #pragma unroll
                for (int ni = 0; ni < 2; ++ni)
                    acc[mi][ni] = __builtin_amdgcn_mfma_f32_16x16x32_bf16(
                        af[mi], bf[ni], acc[mi][ni], 0, 0, 0);
        }
        __syncthreads();   // LDS reads done before next stage overwrites
    }

    if (comp < 4) {
        short* sG = sAB;   // [128][LDP]
        #pragma unroll
        for (int mi = 0; mi < 4; ++mi)
            #pragma unroll
            for (int ni = 0; ni < 2; ++ni)
                #pragma unroll
                for (int r = 0; r < 4; ++r)
                    sG[(64*wr + 16*mi + quad*4 + r) * LDP + 32*wc + 16*ni + lm] =
                        f2bf_s(acc[mi][ni][r]);
        __syncthreads();
        #pragma unroll
        for (int j = 0; j < 4; ++j) {
            int id = tid + 256 * j;
            int row = id >> 3, c8 = id & 7;       // 8 x 16B per row
            uint4 v = *(const uint4*)&sG[row * LDP + c8 * 8];
            *(uint4*)&G[(size_t)(mbase + row) * GN + comp*64 + c8*8] = v;
        }
    } else {
        short* sT = sAB;   // [64][STP]
        const int vcomp = comp - 4;
        const int b = mbase >> 11;
        const int tb = mbase & 2047;
        #pragma unroll
        for (int mi = 0; mi < 4; ++mi)
            #pragma unroll
            for (int ni = 0; ni < 2; ++ni)
                #pragma unroll
                for (int r = 0; r < 4; ++r)
                    sT[(32*wc + 16*ni + lm) * STP + 64*wr + 16*mi + quad*4 + r] =
                        f2bf_s(acc[mi][ni][r]);
        __syncthreads();
        #pragma unroll
        for (int j = 0; j < 4; ++j) {
            int id = tid + 256 * j;
            int h = id >> 4, c = id & 15;         // 16 x 16B per h-row
            uint4 v = *(const uint4*)&sT[h * STP + c * 8];
            *(uint4*)&VT[(((size_t)vcomp*BB + b)*64 + h)*VTP + tb + c*8] = v;
        }
    }
}

// ---------------------------------------------------------------------------
// Kernel 2: MFMA flash attention, log2-domain online softmax.
// Grid is (b, j): linear bid % 8 == b, so ALL blocks of batch b land on XCD b
// (8 XCDs, round-robin dispatch) -> b's G/VT panels (1.5 MB) stay L2-resident,
// K/V loads become L2 hits instead of ~900-cy HBM misses.
// Per iteration: all K loads hoisted to the top (one latency exposure), all V
// loads issued before the softmax stretch (max-tree+exp covers L2 latency).
// ---------------------------------------------------------------------------
#define PLDS 72
#define SC2 0.18033688f      // 0.125 * log2(e): softmax in exp2 domain

__global__ __launch_bounds__(256) void attn_kernel(
    const short* __restrict__ G,
    const short* __restrict__ VT,
    float* __restrict__ out)
{
    __shared__ float comb[4][16][128];
    __shared__ float cmw[4][16], clw[4][16];

    const int tid = threadIdx.x;
    const int wave = tid >> 6, lane = tid & 63;
    const int quad = lane >> 4, lm = lane & 15;
    const int b = blockIdx.x;                               // XCD affinity: bid%8 == b
    const int j = (int)(gridDim.y - 1) - (int)blockIdx.y;   // longest first
    const int qbase = j * 16;
    const int nkt = (j >> 2) + 1;    // k-tiles of 64 tokens

    const short* Qrow = G + ((size_t)(b*TT + qbase + lm)) * GN + 128;
    short8 A1[4], A2[4];
    #pragma unroll
    for (int ks = 0; ks < 4; ++ks)
        A1[ks] = *(const short8*)(Qrow + ks*32 + quad*8);
    A2[0] = A1[2]; A2[1] = A1[3];
    A2[2] = neg8(A1[0]); A2[3] = neg8(A1[1]);

    short8 ones;
    #pragma unroll
    for (int i = 0; i < 8; ++i) ones[i] = (short)0x3F80;   // bf16 1.0

    f32x4 Or[4], Oi[4];
    #pragma unroll
    for (int h = 0; h < 4; ++h)
        #pragma unroll
        for (int r = 0; r < 4; ++r) { Or[h][r] = 0.f; Oi[h][r] = 0.f; }
    f32x4 Ol = {0.f, 0.f, 0.f, 0.f};            // row-sums via ones-MFMA
    float m[4];
    #pragma unroll
    for (int r = 0; r < 4; ++r) m[r] = -INFINITY;

    short* Pw = (short*)&comb[wave][0][0];
    const short* Vrb = VT + (size_t)b * 64 * VTP;
    const short* Vib = VT + ((size_t)BB + b) * 64 * VTP;

    for (int kt = wave; kt < nkt; kt += 4) {
        const int kb = kt * 64;
        const short* Kt = G + ((size_t)(b*TT + kb)) * GN;

        // ---- hoist ALL K loads: one latency exposure instead of 4 ----
        short8 Kf[4][4];
        #pragma unroll
        for (int nt = 0; nt < 4; ++nt) {
            const short* Krow = Kt + (size_t)(nt*16 + lm) * GN;
            #pragma unroll
            for (int ks = 0; ks < 4; ++ks)
                Kf[nt][ks] = *(const short8*)(Krow + ks*32 + quad*8);
        }

        f32x4 mag[4];
        #pragma unroll
        for (int nt = 0; nt < 4; ++nt) {
            f32x4 sr = {0.f,0.f,0.f,0.f}, si = {0.f,0.f,0.f,0.f};
            __builtin_amdgcn_s_setprio(1);
            #pragma unroll
            for (int ks = 0; ks < 4; ++ks) {
                sr = __builtin_amdgcn_mfma_f32_16x16x32_bf16(A1[ks], Kf[nt][ks], sr, 0,0,0);
                si = __builtin_amdgcn_mfma_f32_16x16x32_bf16(A2[ks], Kf[nt][ks], si, 0,0,0);
            }
            __builtin_amdgcn_s_setprio(0);
            int tok = kb + nt*16 + lm;
            #pragma unroll
            for (int r = 0; r < 4; ++r) {
                float v = __builtin_amdgcn_sqrtf(
                              fmaf(sr[r], sr[r], fmaf(si[r], si[r], 1e-4f))) * SC2;
                int qrow = qbase + quad*4 + r;
                mag[nt][r] = (tok > qrow) ? -INFINITY : v;
            }
        }

        // ---- issue V loads now; softmax below hides their latency ----
        short8 Vr[4][2], Vi[4][2];
        #pragma unroll
        for (int ht = 0; ht < 4; ++ht) {
            const short* vr0 = Vrb + (size_t)(ht*16 + lm) * VTP + kb + quad*8;
            const short* vi0 = Vib + (size_t)(ht*16 + lm) * VTP + kb + quad*8;
            Vr[ht][0] = *(const short8*)(vr0);
            Vr[ht][1] = *(const short8*)(vr0 + 32);
            Vi[ht][0] = *(const short8*)(vi0);
            Vi[ht][1] = *(const short8*)(vi0 + 32);
        }

        float tm[4];
        #pragma unroll
        for (int r = 0; r < 4; ++r)
            tm[r] = fmaxf(fmaxf(mag[0][r], mag[1][r]), fmaxf(mag[2][r], mag[3][r]));
        #pragma unroll
        for (int d = 1; d < 16; d <<= 1)
            #pragma unroll
            for (int r = 0; r < 4; ++r)
                tm[r] = fmaxf(tm[r], __shfl_xor(tm[r], d, 16));

        // defer-max: rescale only when the running max actually grows past slack
        int need = (tm[0] > m[0] + 8.f) | (tm[1] > m[1] + 8.f) |
                   (tm[2] > m[2] + 8.f) | (tm[3] > m[3] + 8.f);
        if (__any(need)) {
            float al[4];
            #pragma unroll
            for (int r = 0; r < 4; ++r) {
                float mn = fmaxf(m[r], tm[r]);
                al[r] = __builtin_amdgcn_exp2f(m[r] - mn);
                m[r] = mn;
            }
            #pragma unroll
            for (int h = 0; h < 4; ++h)
                #pragma unroll
                for (int r = 0; r < 4; ++r) { Or[h][r] *= al[r]; Oi[h][r] *= al[r]; }
            #pragma unroll
            for (int r = 0; r < 4; ++r) Ol[r] *= al[r];
        }

        #pragma unroll
        for (int nt = 0; nt < 4; ++nt)
            #pragma unroll
            for (int r = 0; r < 4; ++r) {
                float p = __builtin_amdgcn_exp2f(mag[nt][r] - m[r]);
                Pw[(quad*4 + r) * PLDS + nt*16 + lm] = f2bf_s(p);
            }
        short8 Af0 = *(const short8*)&Pw[lm * PLDS + quad*8];
        short8 Af1 = *(const short8*)&Pw[lm * PLDS + 32 + quad*8];

        __builtin_amdgcn_s_setprio(1);
        Ol = __builtin_amdgcn_mfma_f32_16x16x32_bf16(Af0, ones, Ol, 0,0,0);
        Ol = __builtin_amdgcn_mfma_f32_16x16x32_bf16(Af1, ones, Ol, 0,0,0);
        __builtin_amdgcn_s_setprio(0);

        #pragma unroll
        for (int ht = 0; ht < 4; ++ht) {
            __builtin_amdgcn_s_setprio(1);
            Or[ht] = __builtin_amdgcn_mfma_f32_16x16x32_bf16(Af0, Vr[ht][0], Or[ht], 0,0,0);
            Or[ht] = __builtin_amdgcn_mfma_f32_16x16x32_bf16(Af1, Vr[ht][1], Or[ht], 0,0,0);
            Oi[ht] = __builtin_amdgcn_mfma_f32_16x16x32_bf16(Af0, Vi[ht][0], Oi[ht], 0,0,0);
            Oi[ht] = __builtin_amdgcn_mfma_f32_16x16x32_bf16(Af1, Vi[ht][1], Oi[ht], 0,0,0);
            __builtin_amdgcn_s_setprio(0);
        }
    }

    __syncthreads();

    #pragma unroll
    for (int ht = 0; ht < 4; ++ht)
        #pragma unroll
        for (int r = 0; r < 4; ++r) {
            comb[wave][quad*4 + r][ht*16 + lm]      = Or[ht][r];
            comb[wave][quad*4 + r][64 + ht*16 + lm] = Oi[ht][r];
        }
    if (lm == 0) {
        #pragma unroll
        for (int r = 0; r < 4; ++r) {
            cmw[wave][quad*4 + r] = m[r];
            clw[wave][quad*4 + r] = Ol[r];
        }
    }
    __syncthreads();

    for (int e = tid; e < 16*128; e += 256) {
        int q = e >> 7, h = e & 127;
        float mstar = fmaxf(fmaxf(cmw[0][q], cmw[1][q]), fmaxf(cmw[2][q], cmw[3][q]));
        float osum = 0.f, lsum = 0.f;
        #pragma unroll
        for (int w = 0; w < 4; ++w) {
            float f = __builtin_amdgcn_exp2f(cmw[w][q] - mstar);
            osum = fmaf(f, comb[w][q][h], osum);
            lsum = fmaf(f, clw[w][q], lsum);
        }
        float res = osum / lsum;
        int comp = h >> 6, hh = h & 63;
        out[(size_t)comp * NST + ((size_t)(b*TT + qbase + q)) * HH + hh] = res;
    }
}

extern "C" void kernel_launch(void* const* d_in, const int* in_sizes, int n_in,
                              void* d_out, int out_size, void* d_ws, size_t ws_size,
                              hipStream_t stream)
{
    const float* xr  = (const float*)d_in[0];
    const float* xi  = (const float*)d_in[1];
    const float* Wkr = (const float*)d_in[2];
    const float* Wki = (const float*)d_in[3];
    const float* Wqr = (const float*)d_in[4];
    const float* Wqi = (const float*)d_in[5];
    const float* Wvr = (const float*)d_in[6];
    const float* Wvi = (const float*)d_in[7];

    short* Bt = (short*)d_ws;                               // 1.5 MB
    short* G  = (short*)((char*)d_ws + (2u  << 20));        // 8 MB  [16384][256]
    short* VT = (short*)((char*)d_ws + (11u << 20));        // 4.3 MB [2][8][64][VTP]
    short* X  = (short*)((char*)d_ws + (16u << 20));        // 64 MB [16384][2048] bf16
    float* out = (float*)d_out;

    prep_kernel<<<NN, 256, 0, stream>>>(Wkr, Wki, Wqr, Wqi, Wvr, Wvi, Bt);

    convert_x<<<4096, 256, 0, stream>>>(xr, xi, X);

    dim3 g1(NROW / 128, 6);
    proj_gemm<<<g1, 256, 0, stream>>>(X, Bt, G, VT);

    dim3 g3(BB, TT / 16);   // bid%8 == b -> per-batch XCD affinity
    attn_kernel<<<g3, 256, 0, stream>>>(G, VT, out);
}